// Round 1
// baseline (147.640 us; speedup 1.0000x reference)
//
#include <hip/hip_runtime.h>

#define NF 26
#define ND 32
#define NPAIR 325              // NF*(NF-1)/2
#define ROW_F4 (NF * ND / 4)   // 208 float4 per input batch-row
#define OUT_F4 (NPAIR * ND / 4)// 2600 float4 per output batch-row

__global__ __launch_bounds__(256) void interaction_kernel(
    const float4* __restrict__ in, float4* __restrict__ out)
{
    __shared__ float4 s_row[ROW_F4];
    __shared__ short  s_ai[NPAIR];  // i * (ND/4)
    __shared__ short  s_bj[NPAIR];  // j * (ND/4)

    const int b   = blockIdx.x;
    const int tid = threadIdx.x;

    // Stage this batch element's input row (26*32 fp32 = 208 float4 = 3.25 KB).
    if (tid < ROW_F4) s_row[tid] = in[b * ROW_F4 + tid];

    // Build pair -> (i,j) lookup once per block. Row-major triu order:
    // (i,j), i<j, i outer. Cheap 1-time loop (<=25 iters) per entry.
    for (int p = tid; p < NPAIR; p += 256) {
        int i = 0, s = 0;
        while (s + (NF - 1 - i) <= p) { s += NF - 1 - i; ++i; }
        int j = p - s + i + 1;
        s_ai[p] = (short)(i * (ND / 4));
        s_bj[p] = (short)(j * (ND / 4));
    }
    __syncthreads();

    // Grid-stride over the 2600 output float4s for this b.
    // Consecutive lanes -> consecutive 16B stores: fully coalesced.
    const int base = b * OUT_F4;   // max 16384*2600 = 42.6M < 2^31, int ok
    for (int q = tid; q < OUT_F4; q += 256) {
        const int p  = q >> 3;     // pair index (ND/4 = 8 float4 per pair)
        const int d4 = q & 7;
        const float4 a = s_row[s_ai[p] + d4];
        const float4 v = s_row[s_bj[p] + d4];
        float4 r;
        r.x = a.x * v.x;
        r.y = a.y * v.y;
        r.z = a.z * v.z;
        r.w = a.w * v.w;
        out[base + q] = r;
    }
}

extern "C" void kernel_launch(void* const* d_in, const int* in_sizes, int n_in,
                              void* d_out, int out_size, void* d_ws, size_t ws_size,
                              hipStream_t stream) {
    const float4* in  = (const float4*)d_in[0];
    float4*       out = (float4*)d_out;
    const int B = in_sizes[0] / (NF * ND);   // 16384
    interaction_kernel<<<B, 256, 0, stream>>>(in, out);
}

// Round 2
// 141.557 us; speedup vs baseline: 1.0430x; 1.0430x over previous
//
#include <hip/hip_runtime.h>

#define NF 26
#define ND 32
#define NPAIR 325                 // NF*(NF-1)/2
#define ROW_F4 (NF * ND / 4)      // 208 float4 per input batch-row
#define OUT_F4 (NPAIR * ND / 4)   // 2600 float4 per output batch-row
#define ROWS 4                    // batch rows per block
#define NTHREADS 256
#define KFULL (OUT_F4 / NTHREADS) // 10 full sweeps per row
#define KTAIL (OUT_F4 % NTHREADS) // 40-thread tail

typedef float f32x4 __attribute__((ext_vector_type(4)));

// Compile-time pair table: entry p packs (i*8) | (j*8)<<8 in float4 units.
struct PairTab { unsigned short v[NPAIR]; };
constexpr PairTab make_tab() {
    PairTab t{};
    int n = 0;
    for (int i = 0; i < NF; ++i)
        for (int j = i + 1; j < NF; ++j)
            t.v[n++] = (unsigned short)((i * (ND / 4)) | ((j * (ND / 4)) << 8));
    return t;
}
__constant__ PairTab c_tab = make_tab();

__global__ __launch_bounds__(NTHREADS) void interaction_kernel(
    const f32x4* __restrict__ in, f32x4* __restrict__ out)
{
    __shared__ f32x4 s_row[ROWS * ROW_F4];   // 13 KB

    const int b0  = blockIdx.x * ROWS;
    const int tid = threadIdx.x;

    // Stage ROWS contiguous input rows (832 float4 = 13 KB), fully coalesced.
    const f32x4* src = in + (size_t)b0 * ROW_F4;
    for (int t = tid; t < ROWS * ROW_F4; t += NTHREADS)
        s_row[t] = src[t];

    // Hoist per-thread LDS element offsets to registers (row-relative).
    int aoff[KFULL + 1], boff[KFULL + 1];
    #pragma unroll
    for (int k = 0; k <= KFULL; ++k) {
        const int q = (k < KFULL) ? (tid + k * NTHREADS)
                                  : (KFULL * NTHREADS + (tid < KTAIL ? tid : 0));
        const unsigned int t = c_tab.v[q >> 3];   // pair index = q/8
        const int d = q & 7;
        aoff[k] = (int)(t & 0xffu) + d;
        boff[k] = (int)(t >> 8) + d;
    }

    __syncthreads();

    #pragma unroll 1
    for (int r = 0; r < ROWS; ++r) {
        const f32x4* __restrict__ row = s_row + r * ROW_F4;
        f32x4* __restrict__ dst = out + (size_t)(b0 + r) * OUT_F4;
        #pragma unroll
        for (int k = 0; k < KFULL; ++k) {
            const f32x4 a = row[aoff[k]];
            const f32x4 v = row[boff[k]];
            const f32x4 rr = a * v;
            __builtin_nontemporal_store(rr, dst + tid + k * NTHREADS);
        }
        if (tid < KTAIL) {
            const f32x4 a = row[aoff[KFULL]];
            const f32x4 v = row[boff[KFULL]];
            const f32x4 rr = a * v;
            __builtin_nontemporal_store(rr, dst + KFULL * NTHREADS + tid);
        }
    }
}

extern "C" void kernel_launch(void* const* d_in, const int* in_sizes, int n_in,
                              void* d_out, int out_size, void* d_ws, size_t ws_size,
                              hipStream_t stream) {
    const f32x4* in  = (const f32x4*)d_in[0];
    f32x4*       out = (f32x4*)d_out;
    const int B = in_sizes[0] / (NF * ND);   // 16384
    interaction_kernel<<<B / ROWS, NTHREADS, 0, stream>>>(in, out);
}